// Round 1
// baseline (1927.704 us; speedup 1.0000x reference)
//
#include <hip/hip_runtime.h>

// SpeechVideoCrossAttention on MI355X (gfx950).
//
// Algebraic restructure (q_len == 1):
//   scores[b,h,k] = ln_v[b,k,:] . U[b,:,h] + q_h.bk_h,  U[b,:,h] = Wk[:,hslice] @ q_h
//   context[b,h,:] = pooled[b,h,:] @ Wv[:,hslice] + bv,  pooled = softmax-weighted ln_v
// so the expensive K/V projections (2 x 687 GFLOP) become K=128 / N=128 per-head
// GEMMs (2 x 137 GFLOP). All matmuls: bf16 MFMA 16x16x32, fp32 accum.
//
// Pipeline:
//   1. ln_speech  -> sN bf16 [8192,2048]
//   2. weight prep: WqT/WvT/WoT (transposed bf16), Wkb (bf16)
//   3. gemm: Q = sN @ Wq + bq                      [8192,2048] bf16
//   4. gemm (z=head): U[b,i,h] = Q_h @ Wk_h^T      [B,16,2048] bf16
//   5. attn: fused video-LN (LDS) + scores + softmax (-> probs out)
//            + pooling (overwrites U in place; each (b,h) owned by one wave)
//   6. gemm (z=head): ctx_h = pooled_h @ Wv_h + bv [8192,2048] bf16
//   7. gemm: out = ctx @ Wo + bo                   fp32 -> d_out
// Steps 4-6 chunk over B if ws_size can't hold full U (537 MB).

#define B_TOT 8192
#define E     2048
#define NH    16
#define HD    128
#define KV    10

typedef short bf16x8 __attribute__((ext_vector_type(8)));
typedef float f32x4  __attribute__((ext_vector_type(4)));

__device__ __forceinline__ unsigned short f2bf(float f) {
  unsigned int u = __float_as_uint(f);
  u = (u + 0x7fffu + ((u >> 16) & 1u)) >> 16;   // round-to-nearest-even
  return (unsigned short)u;
}
__device__ __forceinline__ float bf2f(unsigned short h) {
  return __uint_as_float(((unsigned int)h) << 16);
}
__device__ __forceinline__ void unpack8(int4 v, float* f) {
  unsigned int x = (unsigned int)v.x, y = (unsigned int)v.y;
  unsigned int z = (unsigned int)v.z, w = (unsigned int)v.w;
  f[0] = __uint_as_float(x << 16); f[1] = __uint_as_float(x & 0xffff0000u);
  f[2] = __uint_as_float(y << 16); f[3] = __uint_as_float(y & 0xffff0000u);
  f[4] = __uint_as_float(z << 16); f[5] = __uint_as_float(z & 0xffff0000u);
  f[6] = __uint_as_float(w << 16); f[7] = __uint_as_float(w & 0xffff0000u);
}
__device__ __forceinline__ void async16(const void* g, void* l) {
  __builtin_amdgcn_global_load_lds(
      (const __attribute__((address_space(1))) unsigned int*)g,
      (__attribute__((address_space(3))) unsigned int*)l, 16, 0, 0);
}

// ---------------- LayerNorm of speech rows -> bf16 ----------------
__global__ __launch_bounds__(256) void ln_speech_kernel(
    const float* __restrict__ x, const float* __restrict__ g,
    const float* __restrict__ bb, unsigned short* __restrict__ out)
{
  __shared__ float red[8];
  const int tid = threadIdx.x, wave = tid >> 6, lane = tid & 63;
  const long b = blockIdx.x;
  const float4* row = (const float4*)(x + b * E);
  float4 a0 = row[tid], a1 = row[tid + 256];
  float s  = a0.x + a0.y + a0.z + a0.w + a1.x + a1.y + a1.z + a1.w;
  float s2 = a0.x*a0.x + a0.y*a0.y + a0.z*a0.z + a0.w*a0.w
           + a1.x*a1.x + a1.y*a1.y + a1.z*a1.z + a1.w*a1.w;
  #pragma unroll
  for (int off = 32; off; off >>= 1) { s += __shfl_xor(s, off); s2 += __shfl_xor(s2, off); }
  if (lane == 0) { red[wave] = s; red[wave + 4] = s2; }
  __syncthreads();
  s  = red[0] + red[1] + red[2] + red[3];
  s2 = red[4] + red[5] + red[6] + red[7];
  const float mu = s * (1.0f / E);
  const float rs = rsqrtf(s2 * (1.0f / E) - mu * mu + 1e-5f);
  const float4* g4 = (const float4*)g;
  const float4* b4 = (const float4*)bb;
  ushort4* o = (ushort4*)(out + b * E);
  {
    float4 gg = g4[tid], bv = b4[tid];
    ushort4 r;
    r.x = f2bf((a0.x - mu) * rs * gg.x + bv.x);
    r.y = f2bf((a0.y - mu) * rs * gg.y + bv.y);
    r.z = f2bf((a0.z - mu) * rs * gg.z + bv.z);
    r.w = f2bf((a0.w - mu) * rs * gg.w + bv.w);
    o[tid] = r;
  }
  {
    float4 gg = g4[tid + 256], bv = b4[tid + 256];
    ushort4 r;
    r.x = f2bf((a1.x - mu) * rs * gg.x + bv.x);
    r.y = f2bf((a1.y - mu) * rs * gg.y + bv.y);
    r.z = f2bf((a1.z - mu) * rs * gg.z + bv.z);
    r.w = f2bf((a1.w - mu) * rs * gg.w + bv.w);
    o[tid + 256] = r;
  }
}

// ---------------- transpose + cast fp32 -> bf16 (Wq, Wv, Wo) ----------------
__global__ __launch_bounds__(256) void wtrans_kernel(
    const float* __restrict__ Wq, const float* __restrict__ Wv, const float* __restrict__ Wo,
    unsigned short* __restrict__ WqT, unsigned short* __restrict__ WvT, unsigned short* __restrict__ WoT)
{
  __shared__ float t[32][33];
  const float* W; unsigned short* WT;
  if (blockIdx.z == 0)      { W = Wq; WT = WqT; }
  else if (blockIdx.z == 1) { W = Wv; WT = WvT; }
  else                      { W = Wo; WT = WoT; }
  const int tx = threadIdx.x, ty = threadIdx.y;
  const int n0 = blockIdx.x * 32, k0 = blockIdx.y * 32;
  #pragma unroll
  for (int j = 0; j < 4; j++)
    t[ty + 8*j][tx] = W[(long)(k0 + ty + 8*j) * E + n0 + tx];
  __syncthreads();
  #pragma unroll
  for (int j = 0; j < 4; j++)
    WT[(long)(n0 + ty + 8*j) * E + k0 + tx] = f2bf(t[tx][ty + 8*j]);
}

// ---------------- plain cast fp32 -> bf16 (Wk keeps [in][out] layout) --------
__global__ __launch_bounds__(256) void wcast_kernel(
    const float* __restrict__ W, unsigned short* __restrict__ Wb)
{
  const long i = ((long)blockIdx.x * 256 + threadIdx.x) * 4;
  float4 v = *(const float4*)(W + i);
  ushort4 o;
  o.x = f2bf(v.x); o.y = f2bf(v.y); o.z = f2bf(v.z); o.w = f2bf(v.w);
  *(ushort4*)(Wb + i) = o;
}

// ---------------- m97-style bf16 GEMM, B^T input, 128x128 tile, BK=32 --------
// C[m,n] = sum_k A[m,k] * BT[n,k]  (+ bias[n]); z-batched via strides.
template<bool OUT_BF16, bool HAS_BIAS>
__global__ __launch_bounds__(256) void gemm_bt_kernel(
    const unsigned short* __restrict__ A, int lda, long sAz,
    const unsigned short* __restrict__ BT, int ldb, long sBz,
    void* __restrict__ Cv, int ldc, long sCz,
    const float* __restrict__ bias, int sBiasz, int Ksize)
{
  __shared__ unsigned short As[128 * 32];
  __shared__ unsigned short Bs[128 * 32];
  const int tid = threadIdx.x, wave = tid >> 6, lane = tid & 63;
  A  += (long)blockIdx.z * sAz;
  BT += (long)blockIdx.z * sBz;
  const int tileM = blockIdx.x * 128, tileN = blockIdx.y * 128;
  // staging: wave w owns 16-row segments {w, w+4}; lane -> row s*16+l/4, col (l%4)*8
  const int r0 = wave * 16 + (lane >> 2);
  const int cb = (lane & 3) * 8;
  const unsigned short* Ag0 = A  + (long)(tileM + r0) * lda + cb;
  const unsigned short* Ag1 = A  + (long)(tileM + r0 + 64) * lda + cb;
  const unsigned short* Bg0 = BT + (long)(tileN + r0) * ldb + cb;
  const unsigned short* Bg1 = BT + (long)(tileN + r0 + 64) * ldb + cb;
  unsigned short* As0 = As + wave * 512;
  unsigned short* As1 = As + (wave + 4) * 512;
  unsigned short* Bs0 = Bs + wave * 512;
  unsigned short* Bs1 = Bs + (wave + 4) * 512;
  const int wm = wave & 1, wn = wave >> 1;       // 2x2 wave grid, 64x64 each
  const int quad = lane >> 4, l15 = lane & 15;
  const unsigned short* Ard = As + (wm * 64 + l15) * 32 + quad * 8;
  const unsigned short* Brd = Bs + (wn * 64 + l15) * 32 + quad * 8;

  f32x4 acc[4][4] = {};

  for (int k0 = 0; k0 < Ksize; k0 += 32) {
    __syncthreads();                 // previous tile's ds_reads done
    async16(Ag0 + k0, As0);
    async16(Ag1 + k0, As1);
    async16(Bg0 + k0, Bs0);
    async16(Bg1 + k0, Bs1);
    __syncthreads();                 // compiler drains vmcnt before barrier
    bf16x8 af[4], bfv[4];
    #pragma unroll
    for (int im = 0; im < 4; im++) af[im]  = *(const bf16x8*)(Ard + im * 512);
    #pragma unroll
    for (int in = 0; in < 4; in++) bfv[in] = *(const bf16x8*)(Brd + in * 512);
    #pragma unroll
    for (int im = 0; im < 4; im++)
      #pragma unroll
      for (int in = 0; in < 4; in++)
        acc[im][in] = __builtin_amdgcn_mfma_f32_16x16x32_bf16(af[im], bfv[in], acc[im][in], 0, 0, 0);
  }

  const long czoff = (long)blockIdx.z * sCz;
  #pragma unroll
  for (int in = 0; in < 4; in++) {
    const int gn = tileN + wn * 64 + in * 16 + l15;
    const float badd = HAS_BIAS ? bias[(long)blockIdx.z * sBiasz + gn] : 0.0f;
    #pragma unroll
    for (int im = 0; im < 4; im++) {
      const int gm = tileM + wm * 64 + im * 16 + quad * 4;
      #pragma unroll
      for (int r = 0; r < 4; r++) {
        const float v = acc[im][in][r] + badd;
        const long off = czoff + (long)(gm + r) * ldc + gn;
        if (OUT_BF16) ((unsigned short*)Cv)[off] = f2bf(v);
        else          ((float*)Cv)[off] = v;
      }
    }
  }
}

// ---------------- fused video-LN + scores + softmax + pooling ----------------
// One block per batch row. vs = LN(video[b]) bf16 in LDS (40 KB).
// Wave w owns heads {w, w+4, w+8, w+12}; pooled overwrites U[b,h,:] in place.
__global__ __launch_bounds__(256) void attn_kernel(
    const float* __restrict__ video, const float* __restrict__ lvg,
    const float* __restrict__ lvb,
    const unsigned short* __restrict__ Qb, const float* __restrict__ bk,
    unsigned short* __restrict__ U, float* __restrict__ probs,
    const float* __restrict__ alphap, int b_base)
{
  __shared__ unsigned short vs[KV][E];
  const int tid = threadIdx.x, wave = tid >> 6, lane = tid & 63;
  const int bl = blockIdx.x;
  const long b = (long)b_base + bl;
  const float alpha = alphap[0];

  // LayerNorm 10 video rows (wave w owns rows w, w+4, w+8)
  for (int k = wave; k < KV; k += 4) {
    const float4* row = (const float4*)(video + (b * KV + k) * E);
    float4 xv[8];
    float s = 0.f, s2 = 0.f;
    #pragma unroll
    for (int it = 0; it < 8; it++) {
      xv[it] = row[lane + it * 64];
      s  += xv[it].x + xv[it].y + xv[it].z + xv[it].w;
      s2 += xv[it].x*xv[it].x + xv[it].y*xv[it].y + xv[it].z*xv[it].z + xv[it].w*xv[it].w;
    }
    #pragma unroll
    for (int off = 32; off; off >>= 1) { s += __shfl_xor(s, off); s2 += __shfl_xor(s2, off); }
    const float mu = s * (1.0f / E);
    const float rs = rsqrtf(s2 * (1.0f / E) - mu * mu + 1e-5f);
    #pragma unroll
    for (int it = 0; it < 8; it++) {
      const int i4 = lane + it * 64;
      float4 gg = ((const float4*)lvg)[i4];
      float4 bb = ((const float4*)lvb)[i4];
      ushort4 o;
      o.x = f2bf((xv[it].x - mu) * rs * gg.x + bb.x);
      o.y = f2bf((xv[it].y - mu) * rs * gg.y + bb.y);
      o.z = f2bf((xv[it].z - mu) * rs * gg.z + bb.z);
      o.w = f2bf((xv[it].w - mu) * rs * gg.w + bb.w);
      ((ushort4*)&vs[k][0])[i4] = o;
    }
  }
  __syncthreads();

  // scores: acc[hh][k] = vs[k,:] . U[b,:,h]
  float acc[4][KV];
  #pragma unroll
  for (int hh = 0; hh < 4; hh++)
    #pragma unroll
    for (int k = 0; k < KV; k++) acc[hh][k] = 0.f;
  float qdb[4];
  #pragma unroll
  for (int hh = 0; hh < 4; hh++) {         // q_h . bk_h (softmax shift, exact)
    const int h = wave + hh * 4;
    const float q0 = bf2f(Qb[b * E + h * HD + lane]);
    const float q1 = bf2f(Qb[b * E + h * HD + 64 + lane]);
    qdb[hh] = q0 * bk[h * HD + lane] + q1 * bk[h * HD + 64 + lane];
  }
  for (int it = 0; it < 4; it++) {
    const int i0 = lane * 8 + it * 512;
    float uf[4][8];
    #pragma unroll
    for (int hh = 0; hh < 4; hh++) {
      const int h = wave + hh * 4;
      int4 uv = *(const int4*)(U + ((long)bl * NH + h) * E + i0);
      unpack8(uv, uf[hh]);
    }
    #pragma unroll
    for (int k = 0; k < KV; k++) {
      int4 vv = *(const int4*)&vs[k][i0];
      float vf[8]; unpack8(vv, vf);
      #pragma unroll
      for (int hh = 0; hh < 4; hh++)
        #pragma unroll
        for (int j = 0; j < 8; j++)
          acc[hh][k] += uf[hh][j] * vf[j];
    }
  }
  #pragma unroll
  for (int off = 32; off; off >>= 1) {
    #pragma unroll
    for (int hh = 0; hh < 4; hh++) {
      #pragma unroll
      for (int k = 0; k < KV; k++) acc[hh][k] += __shfl_xor(acc[hh][k], off);
      qdb[hh] += __shfl_xor(qdb[hh], off);
    }
  }

  // softmax (redundant across lanes; matches ref: clip then +pos_bias)
  const float rsd = 0.088388347648318447f;   // 1/sqrt(128)
  float p[4][KV];
  #pragma unroll
  for (int hh = 0; hh < 4; hh++) {
    float mx = -1e30f;
    #pragma unroll
    for (int k = 0; k < KV; k++) {
      float sc = (acc[hh][k] + qdb[hh]) * rsd;
      sc = fminf(fmaxf(sc, -1000.f), 1000.f);
      sc += fmaxf(-alpha * (float)(k * k), -10.f);
      p[hh][k] = sc;
      mx = fmaxf(mx, sc);
    }
    float sum = 0.f;
    #pragma unroll
    for (int k = 0; k < KV; k++) { p[hh][k] = __expf(p[hh][k] - mx); sum += p[hh][k]; }
    const float inv = 1.0f / sum;
    #pragma unroll
    for (int k = 0; k < KV; k++) p[hh][k] *= inv;
  }
  if (lane < KV) {
    #pragma unroll
    for (int hh = 0; hh < 4; hh++) {
      const int h = wave + hh * 4;
      float pv = 0.f;
      #pragma unroll
      for (int k = 0; k < KV; k++) if (k == lane) pv = p[hh][k];
      probs[(b * NH + h) * KV + lane] = pv;
    }
  }

  // pooled[b,h,:] = sum_k p_k * vs[k,:]  -> overwrite U (this wave owns these h)
  for (int it = 0; it < 4; it++) {
    const int i0 = lane * 8 + it * 512;
    float pv[4][8];
    #pragma unroll
    for (int hh = 0; hh < 4; hh++)
      #pragma unroll
      for (int j = 0; j < 8; j++) pv[hh][j] = 0.f;
    #pragma unroll
    for (int k = 0; k < KV; k++) {
      int4 vv = *(const int4*)&vs[k][i0];
      float vf[8]; unpack8(vv, vf);
      #pragma unroll
      for (int hh = 0; hh < 4; hh++)
        #pragma unroll
        for (int j = 0; j < 8; j++)
          pv[hh][j] += p[hh][k] * vf[j];
    }
    #pragma unroll
    for (int hh = 0; hh < 4; hh++) {
      const int h = wave + hh * 4;
      unsigned int w0 = (unsigned int)f2bf(pv[hh][0]) | ((unsigned int)f2bf(pv[hh][1]) << 16);
      unsigned int w1 = (unsigned int)f2bf(pv[hh][2]) | ((unsigned int)f2bf(pv[hh][3]) << 16);
      unsigned int w2 = (unsigned int)f2bf(pv[hh][4]) | ((unsigned int)f2bf(pv[hh][5]) << 16);
      unsigned int w3 = (unsigned int)f2bf(pv[hh][6]) | ((unsigned int)f2bf(pv[hh][7]) << 16);
      int4 st; st.x = (int)w0; st.y = (int)w1; st.z = (int)w2; st.w = (int)w3;
      *(int4*)(U + ((long)bl * NH + h) * E + i0) = st;
    }
  }
}

extern "C" void kernel_launch(void* const* d_in, const int* in_sizes, int n_in,
                              void* d_out, int out_size, void* d_ws, size_t ws_size,
                              hipStream_t stream) {
  const float* speech = (const float*)d_in[0];
  const float* video  = (const float*)d_in[1];
  const float* ln_s_g = (const float*)d_in[2];
  const float* ln_s_b = (const float*)d_in[3];
  const float* ln_v_g = (const float*)d_in[4];
  const float* ln_v_b = (const float*)d_in[5];
  const float* Wq = (const float*)d_in[6];
  const float* bq = (const float*)d_in[7];
  const float* Wk = (const float*)d_in[8];
  const float* bk = (const float*)d_in[9];
  const float* Wv = (const float*)d_in[10];
  const float* bv = (const float*)d_in[11];
  const float* Wo = (const float*)d_in[12];
  const float* bo = (const float*)d_in[13];
  const float* alphap = (const float*)d_in[14];

  char* ws = (char*)d_ws;
  unsigned short* sN  = (unsigned short*)(ws);               // 33,554,432 B
  unsigned short* Qb  = (unsigned short*)(ws + 33554432);    // 33,554,432 B
  unsigned short* ctx = (unsigned short*)(ws + 67108864);    // 33,554,432 B
  unsigned short* WqT = (unsigned short*)(ws + 100663296);   //  8,388,608 B
  unsigned short* WvT = (unsigned short*)(ws + 109051904);   //  8,388,608 B
  unsigned short* WoT = (unsigned short*)(ws + 117440512);   //  8,388,608 B
  unsigned short* Wkb = (unsigned short*)(ws + 125829120);   //  8,388,608 B
  unsigned short* U   = (unsigned short*)(ws + 134217728);   // up to 536,870,912 B

  float* out0  = (float*)d_out;
  float* probs = out0 + (long)B_TOT * E;   // attn_probs [B,16,10]

  // chunk B so U fits in workspace (65,536 B per batch row)
  const size_t fixed = 134217728;
  long rows_cap = 0;
  if (ws_size > fixed) rows_cap = (long)((ws_size - fixed) / ((size_t)NH * E * 2));
  int chunk = (int)((rows_cap / 128) * 128);
  if (chunk > B_TOT) chunk = B_TOT;
  if (chunk < 128)   chunk = 128;   // below this the workspace is simply too small

  ln_speech_kernel<<<B_TOT, 256, 0, stream>>>(speech, ln_s_g, ln_s_b, sN);
  wtrans_kernel<<<dim3(64, 64, 3), dim3(32, 8), 0, stream>>>(Wq, Wv, Wo, WqT, WvT, WoT);
  wcast_kernel<<<4096, 256, 0, stream>>>(Wk, Wkb);

  // Q = sN @ Wq + bq
  gemm_bt_kernel<true, true><<<dim3(64, 16, 1), 256, 0, stream>>>(
      sN, E, 0, WqT, E, 0, Qb, E, 0, bq, 0, E);

  for (int b0 = 0; b0 < B_TOT; b0 += chunk) {
    const int rows = (B_TOT - b0 < chunk) ? (B_TOT - b0) : chunk;
    // U[b,i,h] = Q[b, hslice] @ Wk[:, hslice]^T   (K = 128)
    gemm_bt_kernel<true, false><<<dim3(rows / 128, 16, NH), 256, 0, stream>>>(
        Qb + (long)b0 * E, E, HD, Wkb, E, HD, U, NH * E, E, nullptr, 0, HD);
    // fused LN(video) + scores + softmax + pool (U -> pooled in place)
    attn_kernel<<<rows, 256, 0, stream>>>(video, ln_v_g, ln_v_b, Qb, bk, U, probs, alphap, b0);
    // ctx[b, hslice] = pooled[b,h,:] @ Wv[:, hslice] + bv
    gemm_bt_kernel<true, true><<<dim3(rows / 128, 1, NH), 256, 0, stream>>>(
        U, NH * E, E, WvT, E, (long)HD * E, ctx + (long)b0 * E, E, HD, bv, HD, E);
  }

  // out = ctx @ Wo + bo  (fp32)
  gemm_bt_kernel<false, true><<<dim3(64, 16, 1), 256, 0, stream>>>(
      ctx, E, 0, WoT, E, 0, out0, E, 0, bo, 0, E);
}